// Round 13
// baseline (235.022 us; speedup 1.0000x reference)
//
#include <hip/hip_runtime.h>

#define BB 4
#define CIN 32
#define COUT 32
#define TT 48
#define NN 2000
#define EE 16000
#define BT (BB*TT)
#define PADCOL 24576   // padded CSR capacity (16000 + 2000*3 = 22000 max)

// ---- pre: zero CSR arrays + degree counters, AND weight prep (fused) ----
// bid < 96: zeroing (col/wedge 24576, gcnt 2048). bid >= 96: wprep.

__global__ __launch_bounds__(256) void k_pre(
        int* __restrict__ col, float* __restrict__ wedge,
        int* __restrict__ gcnt,
        const float* __restrict__ w1, const float* __restrict__ gw,
        const float* __restrict__ gb, const float* __restrict__ w2,
        const float* __restrict__ cb2,
        float* __restrict__ w1t, float* __restrict__ w2c,
        float* __restrict__ biasE) {
    int bid = blockIdx.x;
    if (bid < 96) {
        int i = bid * 256 + threadIdx.x;
        col[i] = 0; wedge[i] = 0.f;
        if (i < 2048) gcnt[i] = 0;
        return;
    }
    int i = (bid - 96) * 256 + threadIdx.x;
    if (i < 3072) {
        int c = i & 31, r = i >> 5;
        int co = r & 31, k = r >> 5;          // i = (k*32+co)*32 + c
        w1t[i] = w1[c * 96 + co * 3 + k];
        float acc = 0.f;
#pragma unroll
        for (int q = 0; q < 32; q++)
            acc += gw[co * 32 + q] * w2[c * 96 + q * 3 + k];
        w2c[i] = acc;
    } else if (i < 3168) {
        int j = i - 3072;
        int cls = j >> 5, c = j & 31;
        float bk0 = 0.f, bk1 = 0.f, bk2 = 0.f;
#pragma unroll
        for (int co = 0; co < 32; co++) {
            float g = gb[co];
            bk0 += g * w2[c * 96 + co * 3 + 0];
            bk1 += g * w2[c * 96 + co * 3 + 1];
            bk2 += g * w2[c * 96 + co * 3 + 2];
        }
        // class0 (t=0): b2+bk1+bk2 ; class1: all ; class2 (t=47): b2+bk0+bk1
        float v = cb2[c] + bk1;
        if (cls != 0) v += bk0;
        if (cls != 2) v += bk2;
        biasE[j] = v;
    }
}

// ---- parallel in-degree count -------------------------------------------

__global__ __launch_bounds__(256) void k_count(const int* __restrict__ ei,
                                               int* __restrict__ gcnt) {
    int e = blockIdx.x * 256 + threadIdx.x;
    if (e < EE) atomicAdd(&gcnt[ei[EE + e]], 1);
}

// ---- build: WAVE-SHUFFLE scan (2 barriers vs 22), rowptr, degrees -------

__global__ __launch_bounds__(1024) void k_build(
        const int* __restrict__ gcnt,
        int* __restrict__ rowptr, float* __restrict__ dinv2,
        float* __restrict__ dinvg, int* __restrict__ fillptr) {
    __shared__ int wtot[16], woff[16];
    int t = threadIdx.x;
    int i0 = 2 * t, i1 = 2 * t + 1;
    int c0 = (i0 < NN) ? gcnt[i0] : 0;
    int c1 = (i1 < NN) ? gcnt[i1] : 0;
    int a0 = (i0 < NN) ? ((c0 + 3) & ~3) : 0;
    int a1 = (i1 < NN) ? ((c1 + 3) & ~3) : 0;

    int lane = t & 63, w = t >> 6;
    int s = a0 + a1;
#pragma unroll
    for (int d = 1; d < 64; d <<= 1) {
        int v = __shfl_up(s, d, 64);
        if (lane >= d) s += v;
    }
    if (lane == 63) wtot[w] = s;
    __syncthreads();
    if (t == 0) {
        int run = 0;
#pragma unroll
        for (int k = 0; k < 16; k++) { woff[k] = run; run += wtot[k]; }
    }
    __syncthreads();

    int incl = woff[w] + s;          // inclusive scan through element i1
    int b1v = incl;                  // scanned[i1]
    int b0v = incl - a1;             // scanned[i0]

    if (i0 < NN) {
        rowptr[i0 + 1] = b0v;
        float deg = (float)(c0 + 1);
        dinvg[i0] = rsqrtf(deg);
        dinv2[i0] = 1.0f / deg;
        fillptr[i0] = b0v - a0;
    }
    if (i1 < NN) {
        rowptr[i1 + 1] = b1v;
        float deg = (float)(c1 + 1);
        dinvg[i1] = rsqrtf(deg);
        dinv2[i1] = 1.0f / deg;
        fillptr[i1] = b1v - a1;
    }
    if (t == 0) rowptr[0] = 0;
}

// ---- edge fill: parallel across CUs (device-scope atomics) --------------

__global__ void k_fill(const int* __restrict__ ei, int* __restrict__ fillptr,
                       const float* __restrict__ dinvg,
                       int* __restrict__ col, float* __restrict__ wedge) {
    int e = blockIdx.x * blockDim.x + threadIdx.x;
    if (e < EE) {
        int s = ei[e], d = ei[EE + e];
        int pos = atomicAdd(fillptr + d, 1);
        col[pos]   = s;
        wedge[pos] = dinvg[s] * dinvg[d];
    }
}

// ---- conv1: R6 pipelined taps, LOCKED at 256 threads/1536 blocks --------

__global__ __launch_bounds__(256) void k_conv1(const float* __restrict__ x,
                                               const float* __restrict__ w1t,
                                               const float* __restrict__ b1,
                                               float* __restrict__ hbuf) {
    // 1536 blocks: xcd = bid&7 owns t in [xcd*6, xcd*6+6) for each b
    int bid = blockIdx.x;
    int xcd = bid & 7;
    int i   = bid >> 3;              // 0..191
    int nch = i & 7;                 // 8 chunks of 256 nodes
    int r   = i >> 3;                // 0..23
    int tloc = r % 6, b = r / 6;
    int t = xcd * 6 + tloc;
    int n = nch * 256 + threadIdx.x;
    if (n >= NN) return;
    int g = b * TT + t;
    int gb = g >> 3, gsub = g & 7;

    float ha[COUT];
#pragma unroll
    for (int c = 0; c < COUT; c++) ha[c] = b1[c];

    const float* xbase = x + ((size_t)b * CIN * TT) * NN + n;
    bool hasL = (t > 0), hasR = (t < TT - 1);
    const float* pL = xbase + (size_t)(hasL ? t - 1 : 0) * NN;   // clamped: always valid
    const float* pM = xbase + (size_t)t * NN;
    const float* pR = xbase + (size_t)(hasR ? t + 1 : 0) * NN;

    float xa[CIN], xm[CIN];
    // taps L and M both in flight
#pragma unroll
    for (int ci = 0; ci < CIN; ci++) xa[ci] = pL[(size_t)ci * TT * NN];
#pragma unroll
    for (int ci = 0; ci < CIN; ci++) xm[ci] = pM[(size_t)ci * TT * NN];
    __builtin_amdgcn_sched_barrier(0);

    if (hasL) {
        const float* wp = w1t;                    // k=0
#pragma unroll
        for (int ci = 0; ci < CIN; ci++) {
#pragma unroll
            for (int c = 0; c < COUT; c++) ha[c] += xa[ci] * wp[ci * COUT + c];
        }
    }
    __builtin_amdgcn_sched_barrier(0);

    // tap R loads issue here; latency hides under tap M's FMA block below
#pragma unroll
    for (int ci = 0; ci < CIN; ci++) xa[ci] = pR[(size_t)ci * TT * NN];
    __builtin_amdgcn_sched_barrier(0);

    {
        const float* wp = w1t + 1024;             // k=1
#pragma unroll
        for (int ci = 0; ci < CIN; ci++) {
#pragma unroll
            for (int c = 0; c < COUT; c++) ha[c] += xm[ci] * wp[ci * COUT + c];
        }
    }
    __builtin_amdgcn_sched_barrier(0);

    if (hasR) {
        const float* wp = w1t + 2048;             // k=2
#pragma unroll
        for (int ci = 0; ci < CIN; ci++) {
#pragma unroll
            for (int c = 0; c < COUT; c++) ha[c] += xa[ci] * wp[ci * COUT + c];
        }
    }

    float4* pa = (float4*)(hbuf + (((size_t)gb * NN + n) * 8 + gsub) * 32);
#pragma unroll
    for (int q = 0; q < 8; q++)
        pa[q] = make_float4(fmaxf(ha[4*q], 0.f), fmaxf(ha[4*q+1], 0.f),
                            fmaxf(ha[4*q+2], 0.f), fmaxf(ha[4*q+3], 0.f));
}

// ---- GCN aggregate: R13 fat blocks (16 nodes) + prefetched edge loop ----
// 12000 tiny blocks -> 3000 blocks x 4 sub-iterations: amortizes block
// setup 4x. Edge loop prefetches the NEXT (col,wedge) quad while the
// current quad's 4 random gathers are in flight -- removes one L2
// latency per iteration from the dependent chain col->gather->FMA.

__global__ __launch_bounds__(256) void k_agg(const float* __restrict__ hbuf,
                                             const int* __restrict__ rowptr,
                                             const int* __restrict__ col,
                                             const float* __restrict__ wedge,
                                             const float* __restrict__ dinv2,
                                             float* __restrict__ gbuf) {
    // 3000 blocks: 8 xcd-slots x 3 bundle-rows x 125 node-groups of 16
    int bid = blockIdx.x;
    int xcd = bid & 7;
    int q   = bid >> 3;          // 0..374
    int gbr = q / 125;           // 0..2
    int ng  = q % 125;           // nodes ng*16 .. ng*16+15
    int gb  = gbr * 8 + xcd;
    int wid  = threadIdx.x >> 6;
    int lane = threadIdx.x & 63;
    int gsub = lane >> 3;
    int cq   = lane & 7;

    const float* xg = hbuf + (size_t)gb * NN * 256;
    size_t loff = (size_t)gsub * 32 + cq * 4;
    int g = gb * 8 + gsub;

#pragma unroll
    for (int sub = 0; sub < 4; sub++) {
        int n = ng * 16 + sub * 4 + wid;

        float4 self = *(const float4*)(xg + (size_t)n * 256 + loff);
        float dv = dinv2[n];
        float4 acc = make_float4(dv * self.x, dv * self.y, dv * self.z, dv * self.w);

        int j  = rowptr[n];
        int je = rowptr[n + 1];
        if (j < je) {
            int4   cc = *(const int4*)(col + j);
            float4 ww = *(const float4*)(wedge + j);
            while (true) {
                int jn = j + 4;
                bool more = jn < je;
                int4   ccn;
                float4 wwn;
                if (more) {                 // prefetch next quad
                    ccn = *(const int4*)(col + jn);
                    wwn = *(const float4*)(wedge + jn);
                }
                float4 v0 = *(const float4*)(xg + (size_t)cc.x * 256 + loff);
                float4 v1 = *(const float4*)(xg + (size_t)cc.y * 256 + loff);
                float4 v2 = *(const float4*)(xg + (size_t)cc.z * 256 + loff);
                float4 v3 = *(const float4*)(xg + (size_t)cc.w * 256 + loff);
                acc.x += ww.x*v0.x + ww.y*v1.x + ww.z*v2.x + ww.w*v3.x;
                acc.y += ww.x*v0.y + ww.y*v1.y + ww.z*v2.y + ww.w*v3.y;
                acc.z += ww.x*v0.z + ww.y*v1.z + ww.z*v2.z + ww.w*v3.z;
                acc.w += ww.x*v0.w + ww.y*v1.w + ww.z*v2.w + ww.w*v3.w;
                if (!more) break;
                cc = ccn; ww = wwn; j = jn;
            }
        }

        *(float4*)(gbuf + ((size_t)g * NN + n) * 32 + cq * 4) = acc;
    }
}

// ---- conv2: one-output-per-thread + R5-style tap pipeline (unchanged) ---

#define LD32(GV, GP) { \
    _Pragma("unroll") \
    for (int q_ = 0; q_ < 8; q_++) { \
        float4 v_ = (GP)[q_]; \
        GV[4*q_] = v_.x; GV[4*q_+1] = v_.y; GV[4*q_+2] = v_.z; GV[4*q_+3] = v_.w; } }

#define FMA32(ACC, GV, WP) { \
    _Pragma("unroll") \
    for (int cm_ = 0; cm_ < 32; cm_++) { \
        float g_ = GV[cm_]; \
        _Pragma("unroll") \
        for (int c_ = 0; c_ < 32; c_++) ACC[c_] += g_ * (WP)[cm_ * 32 + c_]; } }

__global__ __launch_bounds__(256) void k_conv2(const float* __restrict__ gbuf,
                                               const float* __restrict__ w2c,
                                               const float* __restrict__ biasE,
                                               float* __restrict__ out) {
    int bid  = blockIdx.x;
    int xcd  = bid & 7;
    int slot = bid >> 3;                 // 0..191
    int grp  = xcd * 24 + (slot >> 3);   // 0..191 = b*48 + t
    int nch  = slot & 7;
    int b = grp / TT;
    int t = grp % TT;
    int n = nch * 256 + threadIdx.x;
    if (n >= NN) return;

    bool hasL = (t > 0), hasR = (t < TT - 1);
    const float4* pL = (const float4*)(gbuf + (((size_t)(b * TT + (hasL ? t - 1 : 0))) * NN + n) * CIN);
    const float4* pM = (const float4*)(gbuf + (((size_t)(b * TT + t)) * NN + n) * CIN);
    const float4* pR = (const float4*)(gbuf + (((size_t)(b * TT + (hasR ? t + 1 : 0))) * NN + n) * CIN);

    float o[COUT];
#pragma unroll
    for (int c = 0; c < COUT; c++) o[c] = 0.f;

    float ga[CIN], gm[CIN];
    LD32(ga, pL);                        // tap L in flight
    LD32(gm, pM);                        // tap M in flight
    __builtin_amdgcn_sched_barrier(0);

    if (hasL) { FMA32(o, ga, w2c); }     // k=0
    __builtin_amdgcn_sched_barrier(0);

    LD32(ga, pR);                        // tap R hides under FMA(M)
    __builtin_amdgcn_sched_barrier(0);

    FMA32(o, gm, w2c + 1024);            // k=1
    __builtin_amdgcn_sched_barrier(0);

    if (hasR) { FMA32(o, ga, w2c + 2048); }  // k=2

    int cls = (t == 0) ? 0 : ((t == TT - 1) ? 2 : 1);
    const float* bp = biasE + cls * 32;
#pragma unroll
    for (int c = 0; c < COUT; c++)
        out[(((size_t)b * COUT + c) * TT + t) * NN + n] = o[c] + bp[c];
}

// ---- launch -------------------------------------------------------------

extern "C" void kernel_launch(void* const* d_in, const int* in_sizes, int n_in,
                              void* d_out, int out_size, void* d_ws, size_t ws_size,
                              hipStream_t stream) {
    const float* x     = (const float*)d_in[0];
    const int*   ei    = (const int*)d_in[1];
    const float* w1    = (const float*)d_in[2];
    const float* b1    = (const float*)d_in[3];
    const float* gcn_w = (const float*)d_in[4];
    const float* gcn_b = (const float*)d_in[5];
    const float* w2    = (const float*)d_in[6];
    const float* b2    = (const float*)d_in[7];
    float* out = (float*)d_out;

    const size_t XWB = (size_t)BT * NN * COUT * sizeof(float);  // 49.152 MB
    char* w = (char*)d_ws;
    float* hbuf    = (float*)w;  w += XWB;   // bundled [gb][n][gsub][c]
    float* gbuf    = (float*)w;  w += XWB;   // standard [g][n][c]
    int*   rowptr  = (int*)w;    w += 8192;
    float* dinv2   = (float*)w;  w += 8192;
    float* dinvg   = (float*)w;  w += 8192;
    int*   fillptr = (int*)w;    w += 8192;
    int*   gcnt    = (int*)w;    w += 8192;
    int*   col     = (int*)w;    w += PADCOL * sizeof(int);
    float* wedge   = (float*)w;  w += PADCOL * sizeof(float);
    float* w1t     = (float*)w;  w += 3072 * sizeof(float);
    float* w2c     = (float*)w;  w += 3072 * sizeof(float);
    float* biasE   = (float*)w;  w += 96 * sizeof(float);

    k_pre  <<<dim3(109), dim3(256), 0, stream>>>(col, wedge, gcnt,
                                                 w1, gcn_w, gcn_b, w2, b2,
                                                 w1t, w2c, biasE);
    k_count<<<dim3((EE + 255) / 256), dim3(256), 0, stream>>>(ei, gcnt);
    k_build<<<dim3(1), dim3(1024), 0, stream>>>(gcnt, rowptr, dinv2, dinvg, fillptr);
    k_fill <<<dim3((EE + 255) / 256), dim3(256), 0, stream>>>(ei, fillptr, dinvg, col, wedge);
    k_conv1<<<dim3(1536), dim3(256), 0, stream>>>(x, w1t, b1, hbuf);
    k_agg  <<<dim3(3000), dim3(256), 0, stream>>>(hbuf, rowptr, col, wedge, dinv2, gbuf);
    k_conv2<<<dim3(1536), dim3(256), 0, stream>>>(gbuf, w2c, biasE, out);
}

// Round 14
// 227.305 us; speedup vs baseline: 1.0339x; 1.0339x over previous
//
#include <hip/hip_runtime.h>

#define BB 4
#define CIN 32
#define COUT 32
#define TT 48
#define NN 2000
#define EE 16000
#define BT (BB*TT)
#define PADCOL 24576   // padded CSR capacity (16000 + 2000*3 = 22000 max)

// ---- pre: zero CSR arrays + degree counters, AND weight prep (fused) ----
// bid < 96: zeroing (col/wedge 24576, gcnt 2048). bid >= 96: wprep.

__global__ __launch_bounds__(256) void k_pre(
        int* __restrict__ col, float* __restrict__ wedge,
        int* __restrict__ gcnt,
        const float* __restrict__ w1, const float* __restrict__ gw,
        const float* __restrict__ gb, const float* __restrict__ w2,
        const float* __restrict__ cb2,
        float* __restrict__ w1t, float* __restrict__ w2c,
        float* __restrict__ biasE) {
    int bid = blockIdx.x;
    if (bid < 96) {
        int i = bid * 256 + threadIdx.x;
        col[i] = 0; wedge[i] = 0.f;
        if (i < 2048) gcnt[i] = 0;
        return;
    }
    int i = (bid - 96) * 256 + threadIdx.x;
    if (i < 3072) {
        int c = i & 31, r = i >> 5;
        int co = r & 31, k = r >> 5;          // i = (k*32+co)*32 + c
        w1t[i] = w1[c * 96 + co * 3 + k];
        float acc = 0.f;
#pragma unroll
        for (int q = 0; q < 32; q++)
            acc += gw[co * 32 + q] * w2[c * 96 + q * 3 + k];
        w2c[i] = acc;
    } else if (i < 3168) {
        int j = i - 3072;
        int cls = j >> 5, c = j & 31;
        float bk0 = 0.f, bk1 = 0.f, bk2 = 0.f;
#pragma unroll
        for (int co = 0; co < 32; co++) {
            float g = gb[co];
            bk0 += g * w2[c * 96 + co * 3 + 0];
            bk1 += g * w2[c * 96 + co * 3 + 1];
            bk2 += g * w2[c * 96 + co * 3 + 2];
        }
        // class0 (t=0): b2+bk1+bk2 ; class1: all ; class2 (t=47): b2+bk0+bk1
        float v = cb2[c] + bk1;
        if (cls != 0) v += bk0;
        if (cls != 2) v += bk2;
        biasE[j] = v;
    }
}

// ---- parallel in-degree count -------------------------------------------

__global__ __launch_bounds__(256) void k_count(const int* __restrict__ ei,
                                               int* __restrict__ gcnt) {
    int e = blockIdx.x * 256 + threadIdx.x;
    if (e < EE) atomicAdd(&gcnt[ei[EE + e]], 1);
}

// ---- build: WAVE-SHUFFLE scan (2 barriers vs 22), rowptr, degrees -------

__global__ __launch_bounds__(1024) void k_build(
        const int* __restrict__ gcnt,
        int* __restrict__ rowptr, float* __restrict__ dinv2,
        float* __restrict__ dinvg, int* __restrict__ fillptr) {
    __shared__ int wtot[16], woff[16];
    int t = threadIdx.x;
    int i0 = 2 * t, i1 = 2 * t + 1;
    int c0 = (i0 < NN) ? gcnt[i0] : 0;
    int c1 = (i1 < NN) ? gcnt[i1] : 0;
    int a0 = (i0 < NN) ? ((c0 + 3) & ~3) : 0;
    int a1 = (i1 < NN) ? ((c1 + 3) & ~3) : 0;

    int lane = t & 63, w = t >> 6;
    int s = a0 + a1;
#pragma unroll
    for (int d = 1; d < 64; d <<= 1) {
        int v = __shfl_up(s, d, 64);
        if (lane >= d) s += v;
    }
    if (lane == 63) wtot[w] = s;
    __syncthreads();
    if (t == 0) {
        int run = 0;
#pragma unroll
        for (int k = 0; k < 16; k++) { woff[k] = run; run += wtot[k]; }
    }
    __syncthreads();

    int incl = woff[w] + s;          // inclusive scan through element i1
    int b1v = incl;                  // scanned[i1]
    int b0v = incl - a1;             // scanned[i0]

    if (i0 < NN) {
        rowptr[i0 + 1] = b0v;
        float deg = (float)(c0 + 1);
        dinvg[i0] = rsqrtf(deg);
        dinv2[i0] = 1.0f / deg;
        fillptr[i0] = b0v - a0;
    }
    if (i1 < NN) {
        rowptr[i1 + 1] = b1v;
        float deg = (float)(c1 + 1);
        dinvg[i1] = rsqrtf(deg);
        dinv2[i1] = 1.0f / deg;
        fillptr[i1] = b1v - a1;
    }
    if (t == 0) rowptr[0] = 0;
}

// ---- edge fill: parallel across CUs (device-scope atomics) --------------

__global__ void k_fill(const int* __restrict__ ei, int* __restrict__ fillptr,
                       const float* __restrict__ dinvg,
                       int* __restrict__ col, float* __restrict__ wedge) {
    int e = blockIdx.x * blockDim.x + threadIdx.x;
    if (e < EE) {
        int s = ei[e], d = ei[EE + e];
        int pos = atomicAdd(fillptr + d, 1);
        col[pos]   = s;
        wedge[pos] = dinvg[s] * dinvg[d];
    }
}

// ---- conv1: R6 pipelined taps, LOCKED at 256 threads/1536 blocks --------

__global__ __launch_bounds__(256) void k_conv1(const float* __restrict__ x,
                                               const float* __restrict__ w1t,
                                               const float* __restrict__ b1,
                                               float* __restrict__ hbuf) {
    // 1536 blocks: xcd = bid&7 owns t in [xcd*6, xcd*6+6) for each b
    int bid = blockIdx.x;
    int xcd = bid & 7;
    int i   = bid >> 3;              // 0..191
    int nch = i & 7;                 // 8 chunks of 256 nodes
    int r   = i >> 3;                // 0..23
    int tloc = r % 6, b = r / 6;
    int t = xcd * 6 + tloc;
    int n = nch * 256 + threadIdx.x;
    if (n >= NN) return;
    int g = b * TT + t;
    int gb = g >> 3, gsub = g & 7;

    float ha[COUT];
#pragma unroll
    for (int c = 0; c < COUT; c++) ha[c] = b1[c];

    const float* xbase = x + ((size_t)b * CIN * TT) * NN + n;
    bool hasL = (t > 0), hasR = (t < TT - 1);
    const float* pL = xbase + (size_t)(hasL ? t - 1 : 0) * NN;   // clamped: always valid
    const float* pM = xbase + (size_t)t * NN;
    const float* pR = xbase + (size_t)(hasR ? t + 1 : 0) * NN;

    float xa[CIN], xm[CIN];
    // taps L and M both in flight
#pragma unroll
    for (int ci = 0; ci < CIN; ci++) xa[ci] = pL[(size_t)ci * TT * NN];
#pragma unroll
    for (int ci = 0; ci < CIN; ci++) xm[ci] = pM[(size_t)ci * TT * NN];
    __builtin_amdgcn_sched_barrier(0);

    if (hasL) {
        const float* wp = w1t;                    // k=0
#pragma unroll
        for (int ci = 0; ci < CIN; ci++) {
#pragma unroll
            for (int c = 0; c < COUT; c++) ha[c] += xa[ci] * wp[ci * COUT + c];
        }
    }
    __builtin_amdgcn_sched_barrier(0);

    // tap R loads issue here; latency hides under tap M's FMA block below
#pragma unroll
    for (int ci = 0; ci < CIN; ci++) xa[ci] = pR[(size_t)ci * TT * NN];
    __builtin_amdgcn_sched_barrier(0);

    {
        const float* wp = w1t + 1024;             // k=1
#pragma unroll
        for (int ci = 0; ci < CIN; ci++) {
#pragma unroll
            for (int c = 0; c < COUT; c++) ha[c] += xm[ci] * wp[ci * COUT + c];
        }
    }
    __builtin_amdgcn_sched_barrier(0);

    if (hasR) {
        const float* wp = w1t + 2048;             // k=2
#pragma unroll
        for (int ci = 0; ci < CIN; ci++) {
#pragma unroll
            for (int c = 0; c < COUT; c++) ha[c] += xa[ci] * wp[ci * COUT + c];
        }
    }

    float4* pa = (float4*)(hbuf + (((size_t)gb * NN + n) * 8 + gsub) * 32);
#pragma unroll
    for (int q = 0; q < 8; q++)
        pa[q] = make_float4(fmaxf(ha[4*q], 0.f), fmaxf(ha[4*q+1], 0.f),
                            fmaxf(ha[4*q+2], 0.f), fmaxf(ha[4*q+3], 0.f));
}

// ---- GCN aggregate: R12 form restored (12000 blocks — wave supply wins) -
// R13's 3000-fat-block + prefetch variant regressed +7.6us: this kernel
// is parallelism-limited, not setup-limited. Block count is the currency.

__global__ __launch_bounds__(256) void k_agg(const float* __restrict__ hbuf,
                                             const int* __restrict__ rowptr,
                                             const int* __restrict__ col,
                                             const float* __restrict__ wedge,
                                             const float* __restrict__ dinv2,
                                             float* __restrict__ gbuf) {
    // 12000 blocks: 8 xcd-slots x 3 bundle-rows x 500 node-quads
    int bid = blockIdx.x;
    int xcd = bid & 7;
    int q   = bid >> 3;
    int gbr = q / 500;
    int nch = q % 500;
    int gb  = gbr * 8 + xcd;
    int wid  = threadIdx.x >> 6;
    int lane = threadIdx.x & 63;
    int gsub = lane >> 3;
    int cq   = lane & 7;
    int n    = nch * 4 + wid;

    const float* xg = hbuf + (size_t)gb * NN * 256;
    size_t loff = (size_t)gsub * 32 + cq * 4;

    float4 self = *(const float4*)(xg + (size_t)n * 256 + loff);
    float dv = dinv2[n];
    float4 acc = make_float4(dv * self.x, dv * self.y, dv * self.z, dv * self.w);

    int j  = rowptr[n];
    int je = rowptr[n + 1];
    for (; j < je; j += 4) {
        int4   cc = *(const int4*)(col + j);
        float4 ww = *(const float4*)(wedge + j);
        float4 v0 = *(const float4*)(xg + (size_t)cc.x * 256 + loff);
        float4 v1 = *(const float4*)(xg + (size_t)cc.y * 256 + loff);
        float4 v2 = *(const float4*)(xg + (size_t)cc.z * 256 + loff);
        float4 v3 = *(const float4*)(xg + (size_t)cc.w * 256 + loff);
        acc.x += ww.x*v0.x + ww.y*v1.x + ww.z*v2.x + ww.w*v3.x;
        acc.y += ww.x*v0.y + ww.y*v1.y + ww.z*v2.y + ww.w*v3.y;
        acc.z += ww.x*v0.z + ww.y*v1.z + ww.z*v2.z + ww.w*v3.z;
        acc.w += ww.x*v0.w + ww.y*v1.w + ww.z*v2.w + ww.w*v3.w;
    }

    int g = gb * 8 + gsub;
    *(float4*)(gbuf + ((size_t)g * NN + n) * 32 + cq * 4) = acc;
}

// ---- conv2: one-output-per-thread + R5-style tap pipeline (unchanged) ---

#define LD32(GV, GP) { \
    _Pragma("unroll") \
    for (int q_ = 0; q_ < 8; q_++) { \
        float4 v_ = (GP)[q_]; \
        GV[4*q_] = v_.x; GV[4*q_+1] = v_.y; GV[4*q_+2] = v_.z; GV[4*q_+3] = v_.w; } }

#define FMA32(ACC, GV, WP) { \
    _Pragma("unroll") \
    for (int cm_ = 0; cm_ < 32; cm_++) { \
        float g_ = GV[cm_]; \
        _Pragma("unroll") \
        for (int c_ = 0; c_ < 32; c_++) ACC[c_] += g_ * (WP)[cm_ * 32 + c_]; } }

__global__ __launch_bounds__(256) void k_conv2(const float* __restrict__ gbuf,
                                               const float* __restrict__ w2c,
                                               const float* __restrict__ biasE,
                                               float* __restrict__ out) {
    int bid  = blockIdx.x;
    int xcd  = bid & 7;
    int slot = bid >> 3;                 // 0..191
    int grp  = xcd * 24 + (slot >> 3);   // 0..191 = b*48 + t
    int nch  = slot & 7;
    int b = grp / TT;
    int t = grp % TT;
    int n = nch * 256 + threadIdx.x;
    if (n >= NN) return;

    bool hasL = (t > 0), hasR = (t < TT - 1);
    const float4* pL = (const float4*)(gbuf + (((size_t)(b * TT + (hasL ? t - 1 : 0))) * NN + n) * CIN);
    const float4* pM = (const float4*)(gbuf + (((size_t)(b * TT + t)) * NN + n) * CIN);
    const float4* pR = (const float4*)(gbuf + (((size_t)(b * TT + (hasR ? t + 1 : 0))) * NN + n) * CIN);

    float o[COUT];
#pragma unroll
    for (int c = 0; c < COUT; c++) o[c] = 0.f;

    float ga[CIN], gm[CIN];
    LD32(ga, pL);                        // tap L in flight
    LD32(gm, pM);                        // tap M in flight
    __builtin_amdgcn_sched_barrier(0);

    if (hasL) { FMA32(o, ga, w2c); }     // k=0
    __builtin_amdgcn_sched_barrier(0);

    LD32(ga, pR);                        // tap R hides under FMA(M)
    __builtin_amdgcn_sched_barrier(0);

    FMA32(o, gm, w2c + 1024);            // k=1
    __builtin_amdgcn_sched_barrier(0);

    if (hasR) { FMA32(o, ga, w2c + 2048); }  // k=2

    int cls = (t == 0) ? 0 : ((t == TT - 1) ? 2 : 1);
    const float* bp = biasE + cls * 32;
#pragma unroll
    for (int c = 0; c < COUT; c++)
        out[(((size_t)b * COUT + c) * TT + t) * NN + n] = o[c] + bp[c];
}

// ---- launch -------------------------------------------------------------

extern "C" void kernel_launch(void* const* d_in, const int* in_sizes, int n_in,
                              void* d_out, int out_size, void* d_ws, size_t ws_size,
                              hipStream_t stream) {
    const float* x     = (const float*)d_in[0];
    const int*   ei    = (const int*)d_in[1];
    const float* w1    = (const float*)d_in[2];
    const float* b1    = (const float*)d_in[3];
    const float* gcn_w = (const float*)d_in[4];
    const float* gcn_b = (const float*)d_in[5];
    const float* w2    = (const float*)d_in[6];
    const float* b2    = (const float*)d_in[7];
    float* out = (float*)d_out;

    const size_t XWB = (size_t)BT * NN * COUT * sizeof(float);  // 49.152 MB
    char* w = (char*)d_ws;
    float* hbuf    = (float*)w;  w += XWB;   // bundled [gb][n][gsub][c]
    float* gbuf    = (float*)w;  w += XWB;   // standard [g][n][c]
    int*   rowptr  = (int*)w;    w += 8192;
    float* dinv2   = (float*)w;  w += 8192;
    float* dinvg   = (float*)w;  w += 8192;
    int*   fillptr = (int*)w;    w += 8192;
    int*   gcnt    = (int*)w;    w += 8192;
    int*   col     = (int*)w;    w += PADCOL * sizeof(int);
    float* wedge   = (float*)w;  w += PADCOL * sizeof(float);
    float* w1t     = (float*)w;  w += 3072 * sizeof(float);
    float* w2c     = (float*)w;  w += 3072 * sizeof(float);
    float* biasE   = (float*)w;  w += 96 * sizeof(float);

    k_pre  <<<dim3(109), dim3(256), 0, stream>>>(col, wedge, gcnt,
                                                 w1, gcn_w, gcn_b, w2, b2,
                                                 w1t, w2c, biasE);
    k_count<<<dim3((EE + 255) / 256), dim3(256), 0, stream>>>(ei, gcnt);
    k_build<<<dim3(1), dim3(1024), 0, stream>>>(gcnt, rowptr, dinv2, dinvg, fillptr);
    k_fill <<<dim3((EE + 255) / 256), dim3(256), 0, stream>>>(ei, fillptr, dinvg, col, wedge);
    k_conv1<<<dim3(1536), dim3(256), 0, stream>>>(x, w1t, b1, hbuf);
    k_agg  <<<dim3(12000), dim3(256), 0, stream>>>(hbuf, rowptr, col, wedge, dinv2, gbuf);
    k_conv2<<<dim3(1536), dim3(256), 0, stream>>>(gbuf, w2c, biasE, out);
}